// Round 11
// baseline (142.660 us; speedup 1.0000x reference)
//
#include <hip/hip_runtime.h>

typedef __attribute__((ext_vector_type(8))) short short8;
typedef __attribute__((ext_vector_type(4))) float f32x4;
typedef __attribute__((ext_vector_type(2))) unsigned int u32x2;

#define LN_EPS 1e-5f
#define NSLOPE 0.01f
#define SROW 264   // shorts per s_act row (528B)
#define TROW 76    // shorts per s_embT row (152B, 8B-aligned)

static __device__ __forceinline__ unsigned int bfround(float f){
  union { float f; unsigned int u; } v; v.f = f;
  return v.u + 0x8000u;
}
static __device__ __forceinline__ unsigned short f2bf(float f){
  return (unsigned short)(bfround(f) >> 16);
}
// one VOP3P inst: u32 = (bf16(hi)<<16) | bf16(lo), RNE
static __device__ __forceinline__ unsigned int cvtpk(float lo, float hi){
  unsigned int r;
  asm("v_cvt_pk_bf16_f32 %0, %1, %2" : "=v"(r) : "v"(lo), "v"(hi));
  return r;
}
static __device__ __forceinline__ float bf2f(unsigned short h){
  union { unsigned int u; float f; } v; v.u = ((unsigned int)h) << 16;
  return v.f;
}

// ---------------- prep: weights -> bf16; pad f1_w K 264->288, fc1_w K 8->32 --
__global__ void qnet_prep(const float* __restrict__ fc1_w, const float* __restrict__ fc2_w,
                          const float* __restrict__ fc3_w, const float* __restrict__ f1_w,
                          unsigned short* __restrict__ fc1w_bf, unsigned short* __restrict__ fc2_bf,
                          unsigned short* __restrict__ fc3_bf, unsigned short* __restrict__ f1_bf){
  int i = blockIdx.x * 256 + threadIdx.x;
  if (i < 65536) {
    fc2_bf[i] = f2bf(fc2_w[i]);
  } else if (i < 98304) {
    int j = i - 65536;
    fc3_bf[j] = f2bf(fc3_w[j]);
  } else if (i < 245760) {
    int j = i - 98304;
    int o = j / 288, k = j % 288;
    f1_bf[j] = (k < 264) ? f2bf(f1_w[o*264 + k]) : (unsigned short)0;
  } else {
    int j = i - 245760;           // < 8192
    int c = j >> 5, k = j & 31;
    fc1w_bf[j] = (k < 8) ? f2bf(fc1_w[c*8 + k]) : (unsigned short)0;
  }
}

// ---- fused epilogue (8-wave): bias + LN(over d) + lrelu + pack + store ------
// acc[mt][nt] value at (d = 32*wid+16*mt+4*lg+j, n = 16*nt+lr)
static __device__ __forceinline__ void epi_ln(
    f32x4 (*acc)[4], unsigned short (*s_act)[SROW], float2 (*s_red)[64],
    const float* __restrict__ fcb, const float* __restrict__ g,
    const float* __restrict__ beta, int wid, int lr, int lg)
{
  const int dbase0 = 32*wid + 4*lg;
  float S[4], S2[4];
  #pragma unroll
  for (int nt = 0; nt < 4; nt++){ S[nt] = 0.f; S2[nt] = 0.f; }
  #pragma unroll
  for (int mt = 0; mt < 2; mt++){
    float4 b4 = *(const float4*)(fcb + dbase0 + 16*mt);
    const float* bb = (const float*)&b4;
    #pragma unroll
    for (int nt = 0; nt < 4; nt++)
      #pragma unroll
      for (int j = 0; j < 4; j++){
        float w = acc[mt][nt][j] + bb[j];
        acc[mt][nt][j] = w;
        S[nt] += w; S2[nt] = fmaf(w, w, S2[nt]);
      }
  }
  #pragma unroll
  for (int nt = 0; nt < 4; nt++){
    S[nt]  += __shfl_xor(S[nt], 16, 64);  S[nt]  += __shfl_xor(S[nt], 32, 64);
    S2[nt] += __shfl_xor(S2[nt], 16, 64); S2[nt] += __shfl_xor(S2[nt], 32, 64);
  }
  if (lg == 0){
    #pragma unroll
    for (int nt = 0; nt < 4; nt++){
      float2 p; p.x = S[nt]; p.y = S2[nt];
      s_red[wid][16*nt + lr] = p;
    }
  }
  __syncthreads();   // s_red ready; also fences all waves' act reads vs writes
  float mean[4], rstd[4];
  #pragma unroll
  for (int nt = 0; nt < 4; nt++){
    const int n = 16*nt + lr;
    float s = 0.f, s2 = 0.f;
    #pragma unroll
    for (int w = 0; w < 8; w++){
      float2 p = s_red[w][n];
      s += p.x; s2 += p.y;
    }
    float m = s * (1.f/256.f);
    mean[nt] = m;
    rstd[nt] = rsqrtf(fmaf(s2, 1.f/256.f, -m*m) + LN_EPS);
  }
  #pragma unroll
  for (int mt = 0; mt < 2; mt++){
    float4 g4 = *(const float4*)(g    + dbase0 + 16*mt);
    float4 b4 = *(const float4*)(beta + dbase0 + 16*mt);
    const float* gg = (const float*)&g4;
    const float* bb = (const float*)&b4;
    #pragma unroll
    for (int nt = 0; nt < 4; nt++){
      float y[4];
      #pragma unroll
      for (int j = 0; j < 4; j++){
        float s = rstd[nt] * gg[j];
        float o = fmaf(-mean[nt], s, bb[j]);
        float t = fmaf(acc[mt][nt][j], s, o);
        y[j] = fmaxf(t, NSLOPE * t);
      }
      u32x2 o2; o2[0] = cvtpk(y[0], y[1]); o2[1] = cvtpk(y[2], y[3]);
      *(u32x2*)&s_act[16*nt + lr][dbase0 + 16*mt] = o2;
    }
  }
}

// -------- main fused kernel: one block (512 thr, 8 waves) per b -------------
// wave w owns d-cols [32w, 32w+32) in stages 1-2, [16w,16w+16) in stage 3
__global__ __launch_bounds__(512, 6) void qnet_main(
    const float* __restrict__ x_feats, const int* __restrict__ actions,
    const unsigned short* __restrict__ fc1w_bf, const float* __restrict__ fc1_b,
    const float* __restrict__ ln1_g, const float* __restrict__ ln1_b,
    const unsigned short* __restrict__ fc2_bf, const float* __restrict__ fc2_b,
    const float* __restrict__ ln2_g, const float* __restrict__ ln2_b,
    const unsigned short* __restrict__ fc3_bf, const float* __restrict__ fc3_b,
    unsigned short* __restrict__ fc_in)
{
  __shared__ float s_cur[4];
  __shared__ float s_cnt_clamp;
  __shared__ __align__(16) float s_nb[64][8];
  __shared__ __align__(16) float s_mask[64];
  __shared__ __align__(16) unsigned short s_act[64][SROW];
  __shared__ __align__(16) float2 s_red[8][64];
  __shared__ __align__(16) float s_part[4][128];

  const int tid  = threadIdx.x;
  const int b    = blockIdx.x;
  const int wid  = __builtin_amdgcn_readfirstlane(tid >> 6);
  const int lane = tid & 63;
  const int lr   = lane & 15, lg = lane >> 4;

  // ---- phase 0: load x row (3 + 64*5 floats), mask + count via ballot ------
  const float* xr = x_feats + (size_t)b * 323;
  if (tid < 64){
    const float* p = xr + 3 + 5*tid;
    float v0 = p[0], v1 = p[1], v2 = p[2], v3 = p[3], v4 = p[4];
    float4 q0; q0.x = v0; q0.y = v1; q0.z = v2; q0.w = v3;
    float4 q1; q1.x = v4; q1.y = 0.f; q1.z = 0.f; q1.w = 0.f;
    *(float4*)&s_nb[tid][0] = q0;
    *(float4*)&s_nb[tid][4] = q1;
    bool pr = (v0 != 0.f) || (v1 != 0.f) || (v2 != 0.f) || (v3 != 0.f) || (v4 != 0.f);
    s_mask[tid] = pr ? 1.f : 0.f;
    unsigned long long bal = __ballot(pr);
    if (tid == 0) s_cnt_clamp = fmaxf((float)__popcll(bal), 1.f);
  } else if (tid < 67){
    s_cur[tid - 64] = xr[tid - 64];
  }
  __syncthreads();

  // ---- stage 1: fc1 (K=8 pad 32), A=W1, B=x -> D rows=d ---------------------
  {
    short8 xa[4];
    #pragma unroll
    for (int nt = 0; nt < 4; nt++){
      const int row = 16*nt + lr;
      float v0=0.f,v1=0.f,v2=0.f,v3=0.f,v4=0.f,v5=0.f,v6=0.f,v7=0.f;
      if (lg == 0){
        v0 = s_cur[0]; v1 = s_cur[1]; v2 = s_cur[2];
        float4 nb = *(const float4*)&s_nb[row][0];
        v3 = nb.x; v4 = nb.y; v5 = nb.z; v6 = nb.w; v7 = s_nb[row][4];
      }
      union { short8 s8; unsigned int u[4]; } t;
      t.u[0] = cvtpk(v0, v1); t.u[1] = cvtpk(v2, v3);
      t.u[2] = cvtpk(v4, v5); t.u[3] = cvtpk(v6, v7);
      xa[nt] = t.s8;
    }
    f32x4 acc[2][4];
    const f32x4 z = {0.f,0.f,0.f,0.f};
    #pragma unroll
    for (int mt = 0; mt < 2; mt++)
      #pragma unroll
      for (int nt = 0; nt < 4; nt++) acc[mt][nt] = z;
    #pragma unroll
    for (int mt = 0; mt < 2; mt++){
      short8 bw = *(const short8*)(fc1w_bf + (size_t)(32*wid + 16*mt + lr)*32 + lg*8);
      #pragma unroll
      for (int nt = 0; nt < 4; nt++)
        acc[mt][nt] = __builtin_amdgcn_mfma_f32_16x16x32_bf16(bw, xa[nt], acc[mt][nt], 0, 0, 0);
    }
    epi_ln(acc, s_act, s_red, fc1_b, ln1_g, ln1_b, wid, lr, lg);
  }
  __syncthreads();

  // ---- stage 2: fc2 (256->256), A=W2, B=act1 -------------------------------
  {
    f32x4 acc[2][4];
    const f32x4 z = {0.f,0.f,0.f,0.f};
    #pragma unroll
    for (int mt = 0; mt < 2; mt++)
      #pragma unroll
      for (int nt = 0; nt < 4; nt++) acc[mt][nt] = z;
    #pragma unroll
    for (int kk = 0; kk < 8; kk++){
      const int k0 = kk*32 + lg*8;
      short8 xa[4];
      #pragma unroll
      for (int nt = 0; nt < 4; nt++) xa[nt] = *(const short8*)&s_act[16*nt + lr][k0];
      #pragma unroll
      for (int mt = 0; mt < 2; mt++){
        short8 bw = *(const short8*)(fc2_bf + (size_t)(32*wid + 16*mt + lr)*256 + k0);
        #pragma unroll
        for (int nt = 0; nt < 4; nt++)
          acc[mt][nt] = __builtin_amdgcn_mfma_f32_16x16x32_bf16(bw, xa[nt], acc[mt][nt], 0, 0, 0);
      }
    }
    epi_ln(acc, s_act, s_red, fc2_b, ln2_g, ln2_b, wid, lr, lg);
  }
  __syncthreads();

  // ---- stage 3: fc3 (256->128), A=act2, B=W3 -> D rows=n; transposed store -
  unsigned short (*s_embT)[TROW] = (unsigned short (*)[TROW])&s_act[0][0];
  {
    f32x4 acc3[4];
    const f32x4 z = {0.f,0.f,0.f,0.f};
    #pragma unroll
    for (int m = 0; m < 4; m++) acc3[m] = z;
    #pragma unroll
    for (int kk = 0; kk < 8; kk++){
      const int k0 = kk*32 + lg*8;
      short8 bw = *(const short8*)(fc3_bf + (size_t)(16*wid + lr)*256 + k0);
      #pragma unroll
      for (int m = 0; m < 4; m++){
        short8 a = *(const short8*)&s_act[16*m + lr][k0];
        acc3[m] = __builtin_amdgcn_mfma_f32_16x16x32_bf16(a, bw, acc3[m], 0, 0, 0);
      }
    }
    __syncthreads();   // all waves done reading act2 -> safe to alias s_embT
    const int col = 16*wid + lr;
    const float bias = fc3_b[col];
    #pragma unroll
    for (int m = 0; m < 4; m++){
      u32x2 o;
      o[0] = cvtpk(acc3[m][0] + bias, acc3[m][1] + bias);
      o[1] = cvtpk(acc3[m][2] + bias, acc3[m][3] + bias);
      *(u32x2*)&s_embT[col][16*m + 4*lg] = o;
    }
  }
  __syncthreads();

  // ---- phase 4: masked mean-pool + gather -> fc_in[b][288] -----------------
  {
    const int aidx = actions[b];
    unsigned short* fo = fc_in + (size_t)b * 288;
    {
      const int d = tid & 127, h = tid >> 7;      // h in 0..3, 16 n each
      const unsigned short* er = s_embT[d] + 16*h;
      float ax = 0.f, ay = 0.f;
      #pragma unroll
      for (int u = 0; u < 4; u++){
        u32x2 w2 = *(const u32x2*)(er + 4*u);
        float2 m0 = *(const float2*)&s_mask[16*h + 4*u];
        float2 m1 = *(const float2*)&s_mask[16*h + 4*u + 2];
        unsigned int a0 = w2[0], a1 = w2[1];
        float x0 = __uint_as_float(a0 << 16), x1 = __uint_as_float(a0 & 0xffff0000u);
        float x2 = __uint_as_float(a1 << 16), x3 = __uint_as_float(a1 & 0xffff0000u);
        ax = fmaf(x0, m0.x, ax); ay = fmaf(x1, m0.y, ay);
        ax = fmaf(x2, m1.x, ax); ay = fmaf(x3, m1.y, ay);
      }
      s_part[h][d] = ax + ay;
    }
    __syncthreads();
    if (tid < 128){
      float tot = (s_part[0][tid] + s_part[1][tid]) + (s_part[2][tid] + s_part[3][tid]);
      fo[131 + tid] = f2bf(tot / s_cnt_clamp);  // pooled
      fo[3 + tid]   = s_embT[tid][aidx];        // chosen embed
    } else if (tid < 160){
      const int t = tid - 128;
      if (t < 3)       fo[t] = f2bf(s_cur[t]);
      else if (t < 8)  fo[259 + (t-3)] = f2bf(s_nb[aidx][t-3]);
      else             fo[264 + (t-8)] = 0;   // zero pad K->288
    }
  }
}

// ---------------- head: fc_in[B][288] -> f1 -> LN -> lrelu -> f2 -> out[B] --
__global__ __launch_bounds__(256, 2) void qnet_head(
    const unsigned short* __restrict__ fc_in,   // [B][288] bf16
    const unsigned short* __restrict__ f1_bf,   // [512][288] bf16
    const float* __restrict__ f1_b,
    const float* __restrict__ lnf_g, const float* __restrict__ lnf_b,
    const float* __restrict__ f2_w, const float* __restrict__ f2_b,
    float* __restrict__ out)
{
  __shared__ __align__(16) unsigned short s_fin[16][296];
  __shared__ __align__(16) float s_pre[16][520];
  const int tid = threadIdx.x;
  const int r0  = blockIdx.x * 16;
  const int wid = tid >> 6, lane = tid & 63;
  const int lr  = lane & 15, lg = lane >> 4;

  for (int i = tid; i < 16*36; i += 256){
    int r = i / 36, cc = (i % 36) * 8;
    *(short8*)&s_fin[r][cc] = *(const short8*)(fc_in + (size_t)(r0 + r) * 288 + cc);
  }
  __syncthreads();

  {
    f32x4 acc[8];
    const f32x4 z = {0.f, 0.f, 0.f, 0.f};
    #pragma unroll
    for (int t = 0; t < 8; t++) acc[t] = z;
    #pragma unroll
    for (int kk = 0; kk < 9; kk++){
      const int k0 = kk*32 + lg*8;
      short8 a = *(const short8*)&s_fin[lr][k0];
      #pragma unroll
      for (int t = 0; t < 8; t++){
        short8 bw = *(const short8*)(f1_bf + (size_t)(128*wid + 16*t + lr) * 288 + k0);
        acc[t] = __builtin_amdgcn_mfma_f32_16x16x32_bf16(a, bw, acc[t], 0, 0, 0);
      }
    }
    #pragma unroll
    for (int t = 0; t < 8; t++){
      const int col = 128*wid + 16*t + lr;
      const float bias = f1_b[col];
      #pragma unroll
      for (int j = 0; j < 4; j++){
        const int row = 4*lg + j;
        s_pre[row][col] = acc[t][j] + bias;
      }
    }
  }
  __syncthreads();

  {
    const int c0 = lane * 8;
    float g8[8], b8[8], w8[8];
    #pragma unroll
    for (int j = 0; j < 8; j++){ g8[j] = lnf_g[c0+j]; b8[j] = lnf_b[c0+j]; w8[j] = f2_w[c0+j]; }
    for (int r = wid*4; r < wid*4 + 4; r++){
      float x[8];
      #pragma unroll
      for (int j = 0; j < 8; j++) x[j] = s_pre[r][c0+j];
      float s = 0.f, s2 = 0.f;
      #pragma unroll
      for (int j = 0; j < 8; j++){ s += x[j]; s2 += x[j]*x[j]; }
      #pragma unroll
      for (int m = 1; m < 64; m <<= 1){ s += __shfl_xor(s, m, 64); s2 += __shfl_xor(s2, m, 64); }
      float mean = s * (1.f/512.f);
      float var  = s2 * (1.f/512.f) - mean*mean;
      float rstd = rsqrtf(var + LN_EPS);
      float dot = 0.f;
      #pragma unroll
      for (int j = 0; j < 8; j++){
        float y = (x[j]-mean)*rstd*g8[j] + b8[j];
        y = fmaxf(y, NSLOPE*y);
        dot += y * w8[j];
      }
      #pragma unroll
      for (int m = 1; m < 64; m <<= 1) dot += __shfl_xor(dot, m, 64);
      if (lane == 0) out[r0 + r] = dot + f2_b[0];
    }
  }
}

extern "C" void kernel_launch(void* const* d_in, const int* in_sizes, int n_in,
                              void* d_out, int out_size, void* d_ws, size_t ws_size,
                              hipStream_t stream)
{
  const float* x_feats = (const float*)d_in[0];
  const int*   actions = (const int*)d_in[1];
  const float* fc1_w = (const float*)d_in[2];  const float* fc1_b = (const float*)d_in[3];
  const float* ln1_g = (const float*)d_in[4];  const float* ln1_b = (const float*)d_in[5];
  const float* fc2_w = (const float*)d_in[6];  const float* fc2_b = (const float*)d_in[7];
  const float* ln2_g = (const float*)d_in[8];  const float* ln2_b = (const float*)d_in[9];
  const float* fc3_w = (const float*)d_in[10]; const float* fc3_b = (const float*)d_in[11];
  const float* f1_w  = (const float*)d_in[12]; const float* f1_b  = (const float*)d_in[13];
  const float* lnf_g = (const float*)d_in[14]; const float* lnf_b = (const float*)d_in[15];
  const float* f2_w  = (const float*)d_in[16]; const float* f2_b  = (const float*)d_in[17];

  const int B = in_sizes[1];  // 4096

  unsigned short* fc2_bf  = (unsigned short*)d_ws;
  unsigned short* fc3_bf  = fc2_bf + 256*256;
  unsigned short* f1_bf   = fc3_bf + 128*256;
  unsigned short* fc1w_bf = f1_bf  + 512*288;
  unsigned short* fc_in   = fc1w_bf + 256*32;

  qnet_prep<<<dim3(992), dim3(256), 0, stream>>>(fc1_w, fc2_w, fc3_w, f1_w,
      fc1w_bf, fc2_bf, fc3_bf, f1_bf);
  qnet_main<<<dim3(B), dim3(512), 0, stream>>>(x_feats, actions,
      fc1w_bf, fc1_b, ln1_g, ln1_b, fc2_bf, fc2_b, ln2_g, ln2_b, fc3_bf, fc3_b, fc_in);
  qnet_head<<<dim3(B/16), dim3(256), 0, stream>>>(fc_in, f1_bf, f1_b, lnf_g, lnf_b, f2_w, f2_b,
      (float*)d_out);
}

// Round 12
// 129.344 us; speedup vs baseline: 1.1030x; 1.1030x over previous
//
#include <hip/hip_runtime.h>

typedef __attribute__((ext_vector_type(8))) short short8;
typedef __attribute__((ext_vector_type(4))) float f32x4;
typedef __attribute__((ext_vector_type(2))) unsigned int u32x2;

#define LN_EPS 1e-5f
#define NSLOPE 0.01f
#define SROW 264   // shorts per s_act row (528B)

static __device__ __forceinline__ unsigned int bfround(float f){
  union { float f; unsigned int u; } v; v.f = f;
  return v.u + 0x8000u;
}
static __device__ __forceinline__ unsigned short f2bf(float f){
  return (unsigned short)(bfround(f) >> 16);
}
// one VOP3P inst: u32 = (bf16(hi)<<16) | bf16(lo), RNE
static __device__ __forceinline__ unsigned int cvtpk(float lo, float hi){
  unsigned int r;
  asm("v_cvt_pk_bf16_f32 %0, %1, %2" : "=v"(r) : "v"(lo), "v"(hi));
  return r;
}
static __device__ __forceinline__ float bf2f(unsigned short h){
  union { unsigned int u; float f; } v; v.u = ((unsigned int)h) << 16;
  return v.f;
}

// ---------------- prep: weights -> bf16; pad f1_w K 264->288, fc1_w K 8->32 --
__global__ void qnet_prep(const float* __restrict__ fc1_w, const float* __restrict__ fc2_w,
                          const float* __restrict__ fc3_w, const float* __restrict__ f1_w,
                          unsigned short* __restrict__ fc1w_bf, unsigned short* __restrict__ fc2_bf,
                          unsigned short* __restrict__ fc3_bf, unsigned short* __restrict__ f1_bf){
  int i = blockIdx.x * 256 + threadIdx.x;
  if (i < 65536) {
    fc2_bf[i] = f2bf(fc2_w[i]);
  } else if (i < 98304) {
    int j = i - 65536;
    fc3_bf[j] = f2bf(fc3_w[j]);
  } else if (i < 245760) {
    int j = i - 98304;
    int o = j / 288, k = j % 288;
    f1_bf[j] = (k < 264) ? f2bf(f1_w[o*264 + k]) : (unsigned short)0;
  } else {
    int j = i - 245760;           // < 8192
    int c = j >> 5, k = j & 31;
    fc1w_bf[j] = (k < 8) ? f2bf(fc1_w[c*8 + k]) : (unsigned short)0;
  }
}

// ---- fused epilogue: bias + LN(over d) + lrelu + pack + vectorized store ----
// acc[mt][nt] value at (d = 64*wid+16*mt+4*lg+j, n = 16*nt+lr)   (R4-proven)
static __device__ __forceinline__ void epi_ln(
    f32x4 (*acc)[4], unsigned short (*s_act)[SROW], float2 (*s_red)[64],
    const float* __restrict__ fcb, const float* __restrict__ g,
    const float* __restrict__ beta, int wid, int lr, int lg)
{
  const int dbase0 = 64*wid + 4*lg;
  float4 bias4[4];
  #pragma unroll
  for (int mt = 0; mt < 4; mt++) bias4[mt] = *(const float4*)(fcb + dbase0 + 16*mt);

  float S[4], S2[4];
  #pragma unroll
  for (int nt = 0; nt < 4; nt++){ S[nt] = 0.f; S2[nt] = 0.f; }
  #pragma unroll
  for (int mt = 0; mt < 4; mt++){
    const float* bb = (const float*)&bias4[mt];
    #pragma unroll
    for (int nt = 0; nt < 4; nt++)
      #pragma unroll
      for (int j = 0; j < 4; j++){
        float w = acc[mt][nt][j] + bb[j];
        acc[mt][nt][j] = w;
        S[nt] += w; S2[nt] = fmaf(w, w, S2[nt]);
      }
  }
  #pragma unroll
  for (int nt = 0; nt < 4; nt++){
    S[nt]  += __shfl_xor(S[nt], 16, 64);  S[nt]  += __shfl_xor(S[nt], 32, 64);
    S2[nt] += __shfl_xor(S2[nt], 16, 64); S2[nt] += __shfl_xor(S2[nt], 32, 64);
  }
  if (lg == 0){
    #pragma unroll
    for (int nt = 0; nt < 4; nt++){
      float2 p; p.x = S[nt]; p.y = S2[nt];
      s_red[wid][16*nt + lr] = p;
    }
  }
  __syncthreads();   // s_red ready; also fences all waves' act reads vs writes
  float mean[4], rstd[4];
  #pragma unroll
  for (int nt = 0; nt < 4; nt++){
    const int n = 16*nt + lr;
    float2 p0 = s_red[0][n], p1 = s_red[1][n], p2 = s_red[2][n], p3 = s_red[3][n];
    float s  = (p0.x + p1.x) + (p2.x + p3.x);
    float s2 = (p0.y + p1.y) + (p2.y + p3.y);
    float m  = s * (1.f/256.f);
    mean[nt] = m;
    rstd[nt] = rsqrtf(fmaf(s2, 1.f/256.f, -m*m) + LN_EPS);
  }
  #pragma unroll
  for (int mt = 0; mt < 4; mt++){
    float4 g4 = *(const float4*)(g    + dbase0 + 16*mt);
    float4 b4 = *(const float4*)(beta + dbase0 + 16*mt);
    const float* gg = (const float*)&g4;
    const float* bb = (const float*)&b4;
    #pragma unroll
    for (int nt = 0; nt < 4; nt++){
      float y[4];
      #pragma unroll
      for (int j = 0; j < 4; j++){
        float s = rstd[nt] * gg[j];
        float o = fmaf(-mean[nt], s, bb[j]);
        float t = fmaf(acc[mt][nt][j], s, o);
        y[j] = fmaxf(t, NSLOPE * t);
      }
      u32x2 o2; o2[0] = cvtpk(y[0], y[1]); o2[1] = cvtpk(y[2], y[3]);
      *(u32x2*)&s_act[16*nt + lr][dbase0 + 16*mt] = o2;
    }
  }
}

// ---------------- main fused kernel: one block (256 thr, 4 waves) per b -----
__global__ __launch_bounds__(256, 4) void qnet_main(
    const float* __restrict__ x_feats, const int* __restrict__ actions,
    const unsigned short* __restrict__ fc1w_bf, const float* __restrict__ fc1_b,
    const float* __restrict__ ln1_g, const float* __restrict__ ln1_b,
    const unsigned short* __restrict__ fc2_bf, const float* __restrict__ fc2_b,
    const float* __restrict__ ln2_g, const float* __restrict__ ln2_b,
    const unsigned short* __restrict__ fc3_bf, const float* __restrict__ fc3_b,
    unsigned short* __restrict__ fc_in)
{
  __shared__ float s_cur[4];
  __shared__ float s_cnt_raw, s_cnt_clamp;
  __shared__ __align__(16) float s_nb[64][8];
  __shared__ __align__(16) float s_mask[64];
  __shared__ __align__(16) unsigned short s_act[64][SROW];
  __shared__ __align__(16) float2 s_red[4][64];

  const int tid  = threadIdx.x;
  const int b    = blockIdx.x;
  const int wid  = __builtin_amdgcn_readfirstlane(tid >> 6);
  const int lane = tid & 63;
  const int lr   = lane & 15, lg = lane >> 4;

  // ---- phase 0: load x row (3 + 64*5 floats), mask + count via ballot ------
  const float* xr = x_feats + (size_t)b * 323;
  if (tid < 64){
    const float* p = xr + 3 + 5*tid;
    float v0 = p[0], v1 = p[1], v2 = p[2], v3 = p[3], v4 = p[4];
    float4 q0; q0.x = v0; q0.y = v1; q0.z = v2; q0.w = v3;
    float4 q1; q1.x = v4; q1.y = 0.f; q1.z = 0.f; q1.w = 0.f;
    *(float4*)&s_nb[tid][0] = q0;
    *(float4*)&s_nb[tid][4] = q1;
    bool pr = (v0 != 0.f) || (v1 != 0.f) || (v2 != 0.f) || (v3 != 0.f) || (v4 != 0.f);
    s_mask[tid] = pr ? 1.f : 0.f;
    unsigned long long bal = __ballot(pr);
    if (tid == 0){
      float c = (float)__popcll(bal);
      s_cnt_raw = c;
      s_cnt_clamp = fmaxf(c, 1.f);
    }
  } else if (tid < 67){
    s_cur[tid - 64] = xr[tid - 64];
  }
  __syncthreads();

  // ---- stage 1: fc1 (K=8 pad 32), A=W1, B=x -> D rows=d ---------------------
  {
    short8 xa[4];
    #pragma unroll
    for (int nt = 0; nt < 4; nt++){
      const int row = 16*nt + lr;
      float v0=0.f,v1=0.f,v2=0.f,v3=0.f,v4=0.f,v5=0.f,v6=0.f,v7=0.f;
      if (lg == 0){
        v0 = s_cur[0]; v1 = s_cur[1]; v2 = s_cur[2];
        float4 nb = *(const float4*)&s_nb[row][0];
        v3 = nb.x; v4 = nb.y; v5 = nb.z; v6 = nb.w; v7 = s_nb[row][4];
      }
      union { short8 s8; unsigned int u[4]; } t;
      t.u[0] = cvtpk(v0, v1); t.u[1] = cvtpk(v2, v3);
      t.u[2] = cvtpk(v4, v5); t.u[3] = cvtpk(v6, v7);
      xa[nt] = t.s8;
    }
    f32x4 acc[4][4];
    const f32x4 z = {0.f,0.f,0.f,0.f};
    #pragma unroll
    for (int mt = 0; mt < 4; mt++)
      #pragma unroll
      for (int nt = 0; nt < 4; nt++) acc[mt][nt] = z;
    #pragma unroll
    for (int mt = 0; mt < 4; mt++){
      short8 bw = *(const short8*)(fc1w_bf + (size_t)(64*wid + 16*mt + lr)*32 + lg*8);
      #pragma unroll
      for (int nt = 0; nt < 4; nt++)
        acc[mt][nt] = __builtin_amdgcn_mfma_f32_16x16x32_bf16(bw, xa[nt], acc[mt][nt], 0, 0, 0);
    }
    epi_ln(acc, s_act, s_red, fc1_b, ln1_g, ln1_b, wid, lr, lg);
  }
  __syncthreads();

  // ---- stage 2: fc2 (256->256), A=W2, B=act1 -------------------------------
  {
    f32x4 acc[4][4];
    const f32x4 z = {0.f,0.f,0.f,0.f};
    #pragma unroll
    for (int mt = 0; mt < 4; mt++)
      #pragma unroll
      for (int nt = 0; nt < 4; nt++) acc[mt][nt] = z;
    #pragma unroll
    for (int kk = 0; kk < 8; kk++){
      const int k0 = kk*32 + lg*8;
      short8 xa[4];
      #pragma unroll
      for (int nt = 0; nt < 4; nt++) xa[nt] = *(const short8*)&s_act[16*nt + lr][k0];
      #pragma unroll
      for (int mt = 0; mt < 4; mt++){
        short8 bw = *(const short8*)(fc2_bf + (size_t)(64*wid + 16*mt + lr)*256 + k0);
        #pragma unroll
        for (int nt = 0; nt < 4; nt++)
          acc[mt][nt] = __builtin_amdgcn_mfma_f32_16x16x32_bf16(bw, xa[nt], acc[mt][nt], 0, 0, 0);
      }
    }
    epi_ln(acc, s_act, s_red, fc2_b, ln2_g, ln2_b, wid, lr, lg);
  }
  __syncthreads();

  // ---- stage 3: fc3 (256->128), A=act2, B=W3 -> D rows=n, cols=e -----------
  //      pool + gather entirely in registers; no further barriers needed.
  {
    f32x4 acc3[4][2];
    const f32x4 z = {0.f,0.f,0.f,0.f};
    #pragma unroll
    for (int m = 0; m < 4; m++){ acc3[m][0] = z; acc3[m][1] = z; }
    #pragma unroll
    for (int kk = 0; kk < 8; kk++){
      const int k0 = kk*32 + lg*8;
      short8 a[4];
      #pragma unroll
      for (int m = 0; m < 4; m++) a[m] = *(const short8*)&s_act[16*m + lr][k0];
      #pragma unroll
      for (int t4 = 0; t4 < 2; t4++){
        short8 bw = *(const short8*)(fc3_bf + (size_t)(32*wid + 16*t4 + lr)*256 + k0);
        #pragma unroll
        for (int m = 0; m < 4; m++)
          acc3[m][t4] = __builtin_amdgcn_mfma_f32_16x16x32_bf16(a[m], bw, acc3[m][t4], 0, 0, 0);
      }
    }
    // thread holds n = 16m+4lg+j for embed cols e = 32wid+16t4+lr
    const int aidx  = actions[b];
    const int mhit  = aidx >> 4;
    const int lghit = (aidx >> 2) & 3;
    const int jhit  = aidx & 3;
    float part[2], sel[2];
    part[0] = 0.f; part[1] = 0.f; sel[0] = 0.f; sel[1] = 0.f;
    #pragma unroll
    for (int m = 0; m < 4; m++){
      float4 mk = *(const float4*)&s_mask[16*m + 4*lg];   // broadcast in lg group
      const float* mm = (const float*)&mk;
      #pragma unroll
      for (int j = 0; j < 4; j++){
        const bool hit = (m == mhit) && (j == jhit) && (lg == lghit);
        #pragma unroll
        for (int t4 = 0; t4 < 2; t4++){
          part[t4] = fmaf(mm[j], acc3[m][t4][j], part[t4]);
          if (hit) sel[t4] += acc3[m][t4][j];
        }
      }
    }
    #pragma unroll
    for (int t4 = 0; t4 < 2; t4++){
      part[t4] += __shfl_xor(part[t4], 16, 64);
      part[t4] += __shfl_xor(part[t4], 32, 64);
      sel[t4]  += __shfl_xor(sel[t4], 16, 64);
      sel[t4]  += __shfl_xor(sel[t4], 32, 64);
    }
    unsigned short* fo = fc_in + (size_t)b * 288;
    if (lg == 0){
      #pragma unroll
      for (int t4 = 0; t4 < 2; t4++){
        const int e = 32*wid + 16*t4 + lr;
        const float be = fc3_b[e];
        fo[131 + e] = f2bf(fmaf(be, s_cnt_raw, part[t4]) / s_cnt_clamp); // pooled
        fo[3 + e]   = f2bf(sel[t4] + be);                               // chosen
      }
    }
    if (wid == 3 && lane >= 32){
      const int t = lane - 32;
      if (t < 3)       fo[t] = f2bf(s_cur[t]);
      else if (t < 8)  fo[259 + (t-3)] = f2bf(s_nb[aidx][t-3]);
      else             fo[264 + (t-8)] = 0;   // zero pad K->288
    }
  }
}

// ---------------- head: fc_in[B][288] -> f1 -> LN -> lrelu -> f2 -> out[B] --
__global__ __launch_bounds__(256, 2) void qnet_head(
    const unsigned short* __restrict__ fc_in,   // [B][288] bf16
    const unsigned short* __restrict__ f1_bf,   // [512][288] bf16
    const float* __restrict__ f1_b,
    const float* __restrict__ lnf_g, const float* __restrict__ lnf_b,
    const float* __restrict__ f2_w, const float* __restrict__ f2_b,
    float* __restrict__ out)
{
  __shared__ __align__(16) unsigned short s_fin[16][296];
  __shared__ __align__(16) float s_pre[16][520];
  const int tid = threadIdx.x;
  const int r0  = blockIdx.x * 16;
  const int wid = tid >> 6, lane = tid & 63;
  const int lr  = lane & 15, lg = lane >> 4;

  for (int i = tid; i < 16*36; i += 256){
    int r = i / 36, cc = (i % 36) * 8;
    *(short8*)&s_fin[r][cc] = *(const short8*)(fc_in + (size_t)(r0 + r) * 288 + cc);
  }
  __syncthreads();

  {
    f32x4 acc[8];
    const f32x4 z = {0.f, 0.f, 0.f, 0.f};
    #pragma unroll
    for (int t = 0; t < 8; t++) acc[t] = z;
    #pragma unroll
    for (int kk = 0; kk < 9; kk++){
      const int k0 = kk*32 + lg*8;
      short8 a = *(const short8*)&s_fin[lr][k0];
      #pragma unroll
      for (int t = 0; t < 8; t++){
        short8 bw = *(const short8*)(f1_bf + (size_t)(128*wid + 16*t + lr) * 288 + k0);
        acc[t] = __builtin_amdgcn_mfma_f32_16x16x32_bf16(a, bw, acc[t], 0, 0, 0);
      }
    }
    #pragma unroll
    for (int t = 0; t < 8; t++){
      const int col = 128*wid + 16*t + lr;
      const float bias = f1_b[col];
      #pragma unroll
      for (int j = 0; j < 4; j++){
        const int row = 4*lg + j;
        s_pre[row][col] = acc[t][j] + bias;
      }
    }
  }
  __syncthreads();

  {
    const int c0 = lane * 8;
    float g8[8], b8[8], w8[8];
    #pragma unroll
    for (int j = 0; j < 8; j++){ g8[j] = lnf_g[c0+j]; b8[j] = lnf_b[c0+j]; w8[j] = f2_w[c0+j]; }
    for (int r = wid*4; r < wid*4 + 4; r++){
      float x[8];
      #pragma unroll
      for (int j = 0; j < 8; j++) x[j] = s_pre[r][c0+j];
      float s = 0.f, s2 = 0.f;
      #pragma unroll
      for (int j = 0; j < 8; j++){ s += x[j]; s2 += x[j]*x[j]; }
      #pragma unroll
      for (int m = 1; m < 64; m <<= 1){ s += __shfl_xor(s, m, 64); s2 += __shfl_xor(s2, m, 64); }
      float mean = s * (1.f/512.f);
      float var  = s2 * (1.f/512.f) - mean*mean;
      float rstd = rsqrtf(var + LN_EPS);
      float dot = 0.f;
      #pragma unroll
      for (int j = 0; j < 8; j++){
        float y = (x[j]-mean)*rstd*g8[j] + b8[j];
        y = fmaxf(y, NSLOPE*y);
        dot += y * w8[j];
      }
      #pragma unroll
      for (int m = 1; m < 64; m <<= 1) dot += __shfl_xor(dot, m, 64);
      if (lane == 0) out[r0 + r] = dot + f2_b[0];
    }
  }
}

extern "C" void kernel_launch(void* const* d_in, const int* in_sizes, int n_in,
                              void* d_out, int out_size, void* d_ws, size_t ws_size,
                              hipStream_t stream)
{
  const float* x_feats = (const float*)d_in[0];
  const int*   actions = (const int*)d_in[1];
  const float* fc1_w = (const float*)d_in[2];  const float* fc1_b = (const float*)d_in[3];
  const float* ln1_g = (const float*)d_in[4];  const float* ln1_b = (const float*)d_in[5];
  const float* fc2_w = (const float*)d_in[6];  const float* fc2_b = (const float*)d_in[7];
  const float* ln2_g = (const float*)d_in[8];  const float* ln2_b = (const float*)d_in[9];
  const float* fc3_w = (const float*)d_in[10]; const float* fc3_b = (const float*)d_in[11];
  const float* f1_w  = (const float*)d_in[12]; const float* f1_b  = (const float*)d_in[13];
  const float* lnf_g = (const float*)d_in[14]; const float* lnf_b = (const float*)d_in[15];
  const float* f2_w  = (const float*)d_in[16]; const float* f2_b  = (const float*)d_in[17];

  const int B = in_sizes[1];  // 4096

  unsigned short* fc2_bf  = (unsigned short*)d_ws;
  unsigned short* fc3_bf  = fc2_bf + 256*256;
  unsigned short* f1_bf   = fc3_bf + 128*256;
  unsigned short* fc1w_bf = f1_bf  + 512*288;
  unsigned short* fc_in   = fc1w_bf + 256*32;

  qnet_prep<<<dim3(992), dim3(256), 0, stream>>>(fc1_w, fc2_w, fc3_w, f1_w,
      fc1w_bf, fc2_bf, fc3_bf, f1_bf);
  qnet_main<<<dim3(B), dim3(256), 0, stream>>>(x_feats, actions,
      fc1w_bf, fc1_b, ln1_g, ln1_b, fc2_bf, fc2_b, ln2_g, ln2_b, fc3_bf, fc3_b, fc_in);
  qnet_head<<<dim3(B/16), dim3(256), 0, stream>>>(fc_in, f1_bf, f1_b, lnf_g, lnf_b, f2_w, f2_b,
      (float*)d_out);
}

// Round 13
// 129.270 us; speedup vs baseline: 1.1036x; 1.0006x over previous
//
#include <hip/hip_runtime.h>

typedef __attribute__((ext_vector_type(8))) short short8;
typedef __attribute__((ext_vector_type(4))) float f32x4;
typedef __attribute__((ext_vector_type(2))) unsigned int u32x2;

#define LN_EPS 1e-5f
#define NSLOPE 0.01f
#define SROW 264   // shorts per s_act row (528B)
#define TROW 76    // shorts per s_embT row (152B, 8B-aligned)

static __device__ __forceinline__ unsigned int bfround(float f){
  union { float f; unsigned int u; } v; v.f = f;
  return v.u + 0x8000u;
}
static __device__ __forceinline__ unsigned short f2bf(float f){
  return (unsigned short)(bfround(f) >> 16);
}
// one VOP3P inst: u32 = (bf16(hi)<<16) | bf16(lo), RNE
static __device__ __forceinline__ unsigned int cvtpk(float lo, float hi){
  unsigned int r;
  asm("v_cvt_pk_bf16_f32 %0, %1, %2" : "=v"(r) : "v"(lo), "v"(hi));
  return r;
}
static __device__ __forceinline__ float bf2f(unsigned short h){
  union { unsigned int u; float f; } v; v.u = ((unsigned int)h) << 16;
  return v.f;
}

// ---------------- prep: weights -> bf16; pad f1_w K 264->288, fc1_w K 8->32 --
__global__ void qnet_prep(const float* __restrict__ fc1_w, const float* __restrict__ fc2_w,
                          const float* __restrict__ fc3_w, const float* __restrict__ f1_w,
                          unsigned short* __restrict__ fc1w_bf, unsigned short* __restrict__ fc2_bf,
                          unsigned short* __restrict__ fc3_bf, unsigned short* __restrict__ f1_bf){
  int i = blockIdx.x * 256 + threadIdx.x;
  if (i < 65536) {
    fc2_bf[i] = f2bf(fc2_w[i]);
  } else if (i < 98304) {
    int j = i - 65536;
    fc3_bf[j] = f2bf(fc3_w[j]);
  } else if (i < 245760) {
    int j = i - 98304;
    int o = j / 288, k = j % 288;
    f1_bf[j] = (k < 264) ? f2bf(f1_w[o*264 + k]) : (unsigned short)0;
  } else {
    int j = i - 245760;           // < 8192
    int c = j >> 5, k = j & 31;
    fc1w_bf[j] = (k < 8) ? f2bf(fc1_w[c*8 + k]) : (unsigned short)0;
  }
}

// ---- fused epilogue: bias + LN(over d) + lrelu + pack + vectorized store ----
// acc[mt][nt] value at (d = 64*wid+16*mt+4*lg+j, n = 16*nt+lr)   (R4-proven)
static __device__ __forceinline__ void epi_ln(
    f32x4 (*acc)[4], unsigned short (*s_act)[SROW], float2 (*s_red)[64],
    const float* __restrict__ fcb, const float* __restrict__ g,
    const float* __restrict__ beta, int wid, int lr, int lg)
{
  const int dbase0 = 64*wid + 4*lg;
  float4 bias4[4];
  #pragma unroll
  for (int mt = 0; mt < 4; mt++) bias4[mt] = *(const float4*)(fcb + dbase0 + 16*mt);

  float S[4], S2[4];
  #pragma unroll
  for (int nt = 0; nt < 4; nt++){ S[nt] = 0.f; S2[nt] = 0.f; }
  #pragma unroll
  for (int mt = 0; mt < 4; mt++){
    const float* bb = (const float*)&bias4[mt];
    #pragma unroll
    for (int nt = 0; nt < 4; nt++)
      #pragma unroll
      for (int j = 0; j < 4; j++){
        float w = acc[mt][nt][j] + bb[j];
        acc[mt][nt][j] = w;
        S[nt] += w; S2[nt] = fmaf(w, w, S2[nt]);
      }
  }
  #pragma unroll
  for (int nt = 0; nt < 4; nt++){
    S[nt]  += __shfl_xor(S[nt], 16, 64);  S[nt]  += __shfl_xor(S[nt], 32, 64);
    S2[nt] += __shfl_xor(S2[nt], 16, 64); S2[nt] += __shfl_xor(S2[nt], 32, 64);
  }
  if (lg == 0){
    #pragma unroll
    for (int nt = 0; nt < 4; nt++){
      float2 p; p.x = S[nt]; p.y = S2[nt];
      s_red[wid][16*nt + lr] = p;
    }
  }
  __syncthreads();   // s_red ready; also fences all waves' act reads vs writes
  float mean[4], rstd[4];
  #pragma unroll
  for (int nt = 0; nt < 4; nt++){
    const int n = 16*nt + lr;
    float2 p0 = s_red[0][n], p1 = s_red[1][n], p2 = s_red[2][n], p3 = s_red[3][n];
    float s  = (p0.x + p1.x) + (p2.x + p3.x);
    float s2 = (p0.y + p1.y) + (p2.y + p3.y);
    float m  = s * (1.f/256.f);
    mean[nt] = m;
    rstd[nt] = rsqrtf(fmaf(s2, 1.f/256.f, -m*m) + LN_EPS);
  }
  #pragma unroll
  for (int mt = 0; mt < 4; mt++){
    float4 g4 = *(const float4*)(g    + dbase0 + 16*mt);
    float4 b4 = *(const float4*)(beta + dbase0 + 16*mt);
    const float* gg = (const float*)&g4;
    const float* bb = (const float*)&b4;
    #pragma unroll
    for (int nt = 0; nt < 4; nt++){
      float y[4];
      #pragma unroll
      for (int j = 0; j < 4; j++){
        float s = rstd[nt] * gg[j];
        float o = fmaf(-mean[nt], s, bb[j]);
        float t = fmaf(acc[mt][nt][j], s, o);
        y[j] = fmaxf(t, NSLOPE * t);
      }
      u32x2 o2; o2[0] = cvtpk(y[0], y[1]); o2[1] = cvtpk(y[2], y[3]);
      *(u32x2*)&s_act[16*nt + lr][dbase0 + 16*mt] = o2;
    }
  }
}

// ---------------- main fused kernel: one block (256 thr, 4 waves) per b -----
__global__ __launch_bounds__(256, 4) void qnet_main(
    const float* __restrict__ x_feats, const int* __restrict__ actions,
    const unsigned short* __restrict__ fc1w_bf, const float* __restrict__ fc1_b,
    const float* __restrict__ ln1_g, const float* __restrict__ ln1_b,
    const unsigned short* __restrict__ fc2_bf, const float* __restrict__ fc2_b,
    const float* __restrict__ ln2_g, const float* __restrict__ ln2_b,
    const unsigned short* __restrict__ fc3_bf, const float* __restrict__ fc3_b,
    unsigned short* __restrict__ fc_in)
{
  __shared__ float s_cur[4];
  __shared__ float s_cnt_clamp;
  __shared__ __align__(16) float s_nb[64][8];
  __shared__ __align__(16) float s_mask[64];
  __shared__ __align__(16) unsigned short s_act[64][SROW];
  __shared__ __align__(16) float2 s_red[4][64];
  __shared__ __align__(16) float s_part[2][128];

  const int tid  = threadIdx.x;
  const int b    = blockIdx.x;
  const int wid  = __builtin_amdgcn_readfirstlane(tid >> 6);
  const int lane = tid & 63;
  const int lr   = lane & 15, lg = lane >> 4;

  // ---- phase 0: load x row (3 + 64*5 floats), mask + count via ballot ------
  const float* xr = x_feats + (size_t)b * 323;
  if (tid < 64){
    const float* p = xr + 3 + 5*tid;
    float v0 = p[0], v1 = p[1], v2 = p[2], v3 = p[3], v4 = p[4];
    float4 q0; q0.x = v0; q0.y = v1; q0.z = v2; q0.w = v3;
    float4 q1; q1.x = v4; q1.y = 0.f; q1.z = 0.f; q1.w = 0.f;
    *(float4*)&s_nb[tid][0] = q0;
    *(float4*)&s_nb[tid][4] = q1;
    bool pr = (v0 != 0.f) || (v1 != 0.f) || (v2 != 0.f) || (v3 != 0.f) || (v4 != 0.f);
    s_mask[tid] = pr ? 1.f : 0.f;
    unsigned long long bal = __ballot(pr);
    if (tid == 0) s_cnt_clamp = fmaxf((float)__popcll(bal), 1.f);
  } else if (tid < 67){
    s_cur[tid - 64] = xr[tid - 64];
  }
  __syncthreads();

  // ---- stage 1: fc1 (K=8 pad 32), A=W1, B=x -> D rows=d ---------------------
  {
    short8 xa[4];
    #pragma unroll
    for (int nt = 0; nt < 4; nt++){
      const int row = 16*nt + lr;
      float v0=0.f,v1=0.f,v2=0.f,v3=0.f,v4=0.f,v5=0.f,v6=0.f,v7=0.f;
      if (lg == 0){
        v0 = s_cur[0]; v1 = s_cur[1]; v2 = s_cur[2];
        float4 nb = *(const float4*)&s_nb[row][0];
        v3 = nb.x; v4 = nb.y; v5 = nb.z; v6 = nb.w; v7 = s_nb[row][4];
      }
      union { short8 s8; unsigned int u[4]; } t;
      t.u[0] = cvtpk(v0, v1); t.u[1] = cvtpk(v2, v3);
      t.u[2] = cvtpk(v4, v5); t.u[3] = cvtpk(v6, v7);
      xa[nt] = t.s8;
    }
    f32x4 acc[4][4];
    const f32x4 z = {0.f,0.f,0.f,0.f};
    #pragma unroll
    for (int mt = 0; mt < 4; mt++)
      #pragma unroll
      for (int nt = 0; nt < 4; nt++) acc[mt][nt] = z;
    #pragma unroll
    for (int mt = 0; mt < 4; mt++){
      short8 bw = *(const short8*)(fc1w_bf + (size_t)(64*wid + 16*mt + lr)*32 + lg*8);
      #pragma unroll
      for (int nt = 0; nt < 4; nt++)
        acc[mt][nt] = __builtin_amdgcn_mfma_f32_16x16x32_bf16(bw, xa[nt], acc[mt][nt], 0, 0, 0);
    }
    epi_ln(acc, s_act, s_red, fc1_b, ln1_g, ln1_b, wid, lr, lg);
  }
  __syncthreads();

  // ---- stage 2: fc2 (256->256), A=W2, B=act1 -------------------------------
  {
    f32x4 acc[4][4];
    const f32x4 z = {0.f,0.f,0.f,0.f};
    #pragma unroll
    for (int mt = 0; mt < 4; mt++)
      #pragma unroll
      for (int nt = 0; nt < 4; nt++) acc[mt][nt] = z;
    __builtin_amdgcn_s_setprio(1);
    #pragma unroll
    for (int kk = 0; kk < 8; kk++){
      const int k0 = kk*32 + lg*8;
      short8 xa[4];
      #pragma unroll
      for (int nt = 0; nt < 4; nt++) xa[nt] = *(const short8*)&s_act[16*nt + lr][k0];
      #pragma unroll
      for (int mt = 0; mt < 4; mt++){
        short8 bw = *(const short8*)(fc2_bf + (size_t)(64*wid + 16*mt + lr)*256 + k0);
        #pragma unroll
        for (int nt = 0; nt < 4; nt++)
          acc[mt][nt] = __builtin_amdgcn_mfma_f32_16x16x32_bf16(bw, xa[nt], acc[mt][nt], 0, 0, 0);
      }
    }
    __builtin_amdgcn_s_setprio(0);
    epi_ln(acc, s_act, s_red, fc2_b, ln2_g, ln2_b, wid, lr, lg);
  }
  __syncthreads();

  // ---- stage 3: fc3 (256->128), A=act2, B=W3 -> D rows=n; transposed store -
  unsigned short (*s_embT)[TROW] = (unsigned short (*)[TROW])&s_act[0][0];
  {
    f32x4 acc3[4][2];
    const f32x4 z = {0.f,0.f,0.f,0.f};
    #pragma unroll
    for (int m = 0; m < 4; m++){ acc3[m][0] = z; acc3[m][1] = z; }
    __builtin_amdgcn_s_setprio(1);
    #pragma unroll
    for (int kk = 0; kk < 8; kk++){
      const int k0 = kk*32 + lg*8;
      short8 a[4];
      #pragma unroll
      for (int m = 0; m < 4; m++) a[m] = *(const short8*)&s_act[16*m + lr][k0];
      #pragma unroll
      for (int t4 = 0; t4 < 2; t4++){
        short8 bw = *(const short8*)(fc3_bf + (size_t)(32*wid + 16*t4 + lr)*256 + k0);
        #pragma unroll
        for (int m = 0; m < 4; m++)
          acc3[m][t4] = __builtin_amdgcn_mfma_f32_16x16x32_bf16(a[m], bw, acc3[m][t4], 0, 0, 0);
      }
    }
    __builtin_amdgcn_s_setprio(0);
    __syncthreads();   // all waves done reading act2 -> safe to alias s_embT
    #pragma unroll
    for (int t4 = 0; t4 < 2; t4++){
      const int col = 32*wid + 16*t4 + lr;
      const float bias = fc3_b[col];
      #pragma unroll
      for (int m = 0; m < 4; m++){
        u32x2 o;
        o[0] = cvtpk(acc3[m][t4][0] + bias, acc3[m][t4][1] + bias);
        o[1] = cvtpk(acc3[m][t4][2] + bias, acc3[m][t4][3] + bias);
        *(u32x2*)&s_embT[col][16*m + 4*lg] = o;
      }
    }
  }
  __syncthreads();

  // ---- phase 4: masked mean-pool + gather -> fc_in[b][288] -----------------
  {
    const int aidx = actions[b];
    unsigned short* fo = fc_in + (size_t)b * 288;
    {
      const int d = tid & 127, h = tid >> 7;
      const unsigned short* er = s_embT[d] + 32*h;
      float ax = 0.f, ay = 0.f;
      #pragma unroll
      for (int u = 0; u < 8; u++){
        u32x2 w2 = *(const u32x2*)(er + 4*u);
        float2 m0 = *(const float2*)&s_mask[32*h + 4*u];
        float2 m1 = *(const float2*)&s_mask[32*h + 4*u + 2];
        unsigned int a0 = w2[0], a1 = w2[1];
        float x0 = __uint_as_float(a0 << 16), x1 = __uint_as_float(a0 & 0xffff0000u);
        float x2 = __uint_as_float(a1 << 16), x3 = __uint_as_float(a1 & 0xffff0000u);
        ax = fmaf(x0, m0.x, ax); ay = fmaf(x1, m0.y, ay);
        ax = fmaf(x2, m1.x, ax); ay = fmaf(x3, m1.y, ay);
      }
      s_part[h][d] = ax + ay;
    }
    __syncthreads();
    if (tid < 128){
      float tot = s_part[0][tid] + s_part[1][tid];
      fo[131 + tid] = f2bf(tot / s_cnt_clamp);  // pooled
      fo[3 + tid]   = s_embT[tid][aidx];        // chosen embed
    } else if (tid < 160){
      const int t = tid - 128;
      if (t < 3)       fo[t] = f2bf(s_cur[t]);
      else if (t < 8)  fo[259 + (t-3)] = f2bf(s_nb[aidx][t-3]);
      else             fo[264 + (t-8)] = 0;   // zero pad K->288
    }
  }
}

// ---------------- head: fc_in[B][288] -> f1 -> LN -> lrelu -> f2 -> out[B] --
__global__ __launch_bounds__(256, 2) void qnet_head(
    const unsigned short* __restrict__ fc_in,   // [B][288] bf16
    const unsigned short* __restrict__ f1_bf,   // [512][288] bf16
    const float* __restrict__ f1_b,
    const float* __restrict__ lnf_g, const float* __restrict__ lnf_b,
    const float* __restrict__ f2_w, const float* __restrict__ f2_b,
    float* __restrict__ out)
{
  __shared__ __align__(16) unsigned short s_fin[16][296];
  __shared__ __align__(16) float s_pre[16][520];
  const int tid = threadIdx.x;
  const int r0  = blockIdx.x * 16;
  const int wid = tid >> 6, lane = tid & 63;
  const int lr  = lane & 15, lg = lane >> 4;

  for (int i = tid; i < 16*36; i += 256){
    int r = i / 36, cc = (i % 36) * 8;
    *(short8*)&s_fin[r][cc] = *(const short8*)(fc_in + (size_t)(r0 + r) * 288 + cc);
  }
  __syncthreads();

  {
    f32x4 acc[8];
    const f32x4 z = {0.f, 0.f, 0.f, 0.f};
    #pragma unroll
    for (int t = 0; t < 8; t++) acc[t] = z;
    #pragma unroll
    for (int kk = 0; kk < 9; kk++){
      const int k0 = kk*32 + lg*8;
      short8 a = *(const short8*)&s_fin[lr][k0];
      #pragma unroll
      for (int t = 0; t < 8; t++){
        short8 bw = *(const short8*)(f1_bf + (size_t)(128*wid + 16*t + lr) * 288 + k0);
        acc[t] = __builtin_amdgcn_mfma_f32_16x16x32_bf16(a, bw, acc[t], 0, 0, 0);
      }
    }
    #pragma unroll
    for (int t = 0; t < 8; t++){
      const int col = 128*wid + 16*t + lr;
      const float bias = f1_b[col];
      #pragma unroll
      for (int j = 0; j < 4; j++){
        const int row = 4*lg + j;
        s_pre[row][col] = acc[t][j] + bias;
      }
    }
  }
  __syncthreads();

  {
    const int c0 = lane * 8;
    float g8[8], b8[8], w8[8];
    #pragma unroll
    for (int j = 0; j < 8; j++){ g8[j] = lnf_g[c0+j]; b8[j] = lnf_b[c0+j]; w8[j] = f2_w[c0+j]; }
    for (int r = wid*4; r < wid*4 + 4; r++){
      float x[8];
      #pragma unroll
      for (int j = 0; j < 8; j++) x[j] = s_pre[r][c0+j];
      float s = 0.f, s2 = 0.f;
      #pragma unroll
      for (int j = 0; j < 8; j++){ s += x[j]; s2 += x[j]*x[j]; }
      #pragma unroll
      for (int m = 1; m < 64; m <<= 1){ s += __shfl_xor(s, m, 64); s2 += __shfl_xor(s2, m, 64); }
      float mean = s * (1.f/512.f);
      float var  = s2 * (1.f/512.f) - mean*mean;
      float rstd = rsqrtf(var + LN_EPS);
      float dot = 0.f;
      #pragma unroll
      for (int j = 0; j < 8; j++){
        float y = (x[j]-mean)*rstd*g8[j] + b8[j];
        y = fmaxf(y, NSLOPE*y);
        dot += y * w8[j];
      }
      #pragma unroll
      for (int m = 1; m < 64; m <<= 1) dot += __shfl_xor(dot, m, 64);
      if (lane == 0) out[r0 + r] = dot + f2_b[0];
    }
  }
}

extern "C" void kernel_launch(void* const* d_in, const int* in_sizes, int n_in,
                              void* d_out, int out_size, void* d_ws, size_t ws_size,
                              hipStream_t stream)
{
  const float* x_feats = (const float*)d_in[0];
  const int*   actions = (const int*)d_in[1];
  const float* fc1_w = (const float*)d_in[2];  const float* fc1_b = (const float*)d_in[3];
  const float* ln1_g = (const float*)d_in[4];  const float* ln1_b = (const float*)d_in[5];
  const float* fc2_w = (const float*)d_in[6];  const float* fc2_b = (const float*)d_in[7];
  const float* ln2_g = (const float*)d_in[8];  const float* ln2_b = (const float*)d_in[9];
  const float* fc3_w = (const float*)d_in[10]; const float* fc3_b = (const float*)d_in[11];
  const float* f1_w  = (const float*)d_in[12]; const float* f1_b  = (const float*)d_in[13];
  const float* lnf_g = (const float*)d_in[14]; const float* lnf_b = (const float*)d_in[15];
  const float* f2_w  = (const float*)d_in[16]; const float* f2_b  = (const float*)d_in[17];

  const int B = in_sizes[1];  // 4096

  unsigned short* fc2_bf  = (unsigned short*)d_ws;
  unsigned short* fc3_bf  = fc2_bf + 256*256;
  unsigned short* f1_bf   = fc3_bf + 128*256;
  unsigned short* fc1w_bf = f1_bf  + 512*288;
  unsigned short* fc_in   = fc1w_bf + 256*32;

  qnet_prep<<<dim3(992), dim3(256), 0, stream>>>(fc1_w, fc2_w, fc3_w, f1_w,
      fc1w_bf, fc2_bf, fc3_bf, f1_bf);
  qnet_main<<<dim3(B), dim3(256), 0, stream>>>(x_feats, actions,
      fc1w_bf, fc1_b, ln1_g, ln1_b, fc2_bf, fc2_b, ln2_g, ln2_b, fc3_bf, fc3_b, fc_in);
  qnet_head<<<dim3(B/16), dim3(256), 0, stream>>>(fc_in, f1_bf, f1_b, lnf_g, lnf_b, f2_w, f2_b,
      (float*)d_out);
}

// Round 14
// 126.415 us; speedup vs baseline: 1.1285x; 1.0226x over previous
//
#include <hip/hip_runtime.h>

typedef __attribute__((ext_vector_type(8))) short short8;
typedef __attribute__((ext_vector_type(4))) float f32x4;
typedef __attribute__((ext_vector_type(2))) unsigned int u32x2;

#define LN_EPS 1e-5f
#define NSLOPE 0.01f
#define SROW 264   // shorts per s_act row (528B)
#define TROW 76    // shorts per s_embT row (152B, 8B-aligned)

static __device__ __forceinline__ unsigned int bfround(float f){
  union { float f; unsigned int u; } v; v.f = f;
  return v.u + 0x8000u;
}
static __device__ __forceinline__ unsigned short f2bf(float f){
  return (unsigned short)(bfround(f) >> 16);
}
// one VOP3P inst: u32 = (bf16(hi)<<16) | bf16(lo), RNE
static __device__ __forceinline__ unsigned int cvtpk(float lo, float hi){
  unsigned int r;
  asm("v_cvt_pk_bf16_f32 %0, %1, %2" : "=v"(r) : "v"(lo), "v"(hi));
  return r;
}
static __device__ __forceinline__ float bf2f(unsigned short h){
  union { unsigned int u; float f; } v; v.u = ((unsigned int)h) << 16;
  return v.f;
}

// ---------------- prep: weights -> bf16; pad f1_w K 264->288, fc1_w K 8->32 --
__global__ void qnet_prep(const float* __restrict__ fc1_w, const float* __restrict__ fc2_w,
                          const float* __restrict__ fc3_w, const float* __restrict__ f1_w,
                          unsigned short* __restrict__ fc1w_bf, unsigned short* __restrict__ fc2_bf,
                          unsigned short* __restrict__ fc3_bf, unsigned short* __restrict__ f1_bf){
  int i = blockIdx.x * 256 + threadIdx.x;
  if (i < 65536) {
    fc2_bf[i] = f2bf(fc2_w[i]);
  } else if (i < 98304) {
    int j = i - 65536;
    fc3_bf[j] = f2bf(fc3_w[j]);
  } else if (i < 245760) {
    int j = i - 98304;
    int o = j / 288, k = j % 288;
    f1_bf[j] = (k < 264) ? f2bf(f1_w[o*264 + k]) : (unsigned short)0;
  } else {
    int j = i - 245760;           // < 8192
    int c = j >> 5, k = j & 31;
    fc1w_bf[j] = (k < 8) ? f2bf(fc1_w[c*8 + k]) : (unsigned short)0;
  }
}

// ---- fused epilogue: bias + LN(over d) + lrelu + pack + vectorized store ----
// acc[mt][nt] value at (d = 64*wid+16*mt+4*lg+j, n = 16*nt+lr)   (R4-proven)
static __device__ __forceinline__ void epi_ln(
    f32x4 (*acc)[4], unsigned short (*s_act)[SROW], float2 (*s_red)[64],
    const float* __restrict__ fcb, const float* __restrict__ g,
    const float* __restrict__ beta, int wid, int lr, int lg)
{
  const int dbase0 = 64*wid + 4*lg;
  float4 bias4[4];
  #pragma unroll
  for (int mt = 0; mt < 4; mt++) bias4[mt] = *(const float4*)(fcb + dbase0 + 16*mt);

  float S[4], S2[4];
  #pragma unroll
  for (int nt = 0; nt < 4; nt++){ S[nt] = 0.f; S2[nt] = 0.f; }
  #pragma unroll
  for (int mt = 0; mt < 4; mt++){
    const float* bb = (const float*)&bias4[mt];
    #pragma unroll
    for (int nt = 0; nt < 4; nt++)
      #pragma unroll
      for (int j = 0; j < 4; j++){
        float w = acc[mt][nt][j] + bb[j];
        acc[mt][nt][j] = w;
        S[nt] += w; S2[nt] = fmaf(w, w, S2[nt]);
      }
  }
  #pragma unroll
  for (int nt = 0; nt < 4; nt++){
    S[nt]  += __shfl_xor(S[nt], 16, 64);  S[nt]  += __shfl_xor(S[nt], 32, 64);
    S2[nt] += __shfl_xor(S2[nt], 16, 64); S2[nt] += __shfl_xor(S2[nt], 32, 64);
  }
  if (lg == 0){
    #pragma unroll
    for (int nt = 0; nt < 4; nt++){
      float2 p; p.x = S[nt]; p.y = S2[nt];
      s_red[wid][16*nt + lr] = p;
    }
  }
  __syncthreads();   // s_red ready; also fences all waves' act reads vs writes
  float mean[4], rstd[4];
  #pragma unroll
  for (int nt = 0; nt < 4; nt++){
    const int n = 16*nt + lr;
    float2 p0 = s_red[0][n], p1 = s_red[1][n], p2 = s_red[2][n], p3 = s_red[3][n];
    float s  = (p0.x + p1.x) + (p2.x + p3.x);
    float s2 = (p0.y + p1.y) + (p2.y + p3.y);
    float m  = s * (1.f/256.f);
    mean[nt] = m;
    rstd[nt] = rsqrtf(fmaf(s2, 1.f/256.f, -m*m) + LN_EPS);
  }
  #pragma unroll
  for (int mt = 0; mt < 4; mt++){
    float4 g4 = *(const float4*)(g    + dbase0 + 16*mt);
    float4 b4 = *(const float4*)(beta + dbase0 + 16*mt);
    const float* gg = (const float*)&g4;
    const float* bb = (const float*)&b4;
    #pragma unroll
    for (int nt = 0; nt < 4; nt++){
      float y[4];
      #pragma unroll
      for (int j = 0; j < 4; j++){
        float s = rstd[nt] * gg[j];
        float o = fmaf(-mean[nt], s, bb[j]);
        float t = fmaf(acc[mt][nt][j], s, o);
        y[j] = fmaxf(t, NSLOPE * t);
      }
      u32x2 o2; o2[0] = cvtpk(y[0], y[1]); o2[1] = cvtpk(y[2], y[3]);
      *(u32x2*)&s_act[16*nt + lr][dbase0 + 16*mt] = o2;
    }
  }
}

// ---------------- main fused kernel: one block (256 thr, 4 waves) per b -----
__global__ __launch_bounds__(256, 4) void qnet_main(
    const float* __restrict__ x_feats, const int* __restrict__ actions,
    const unsigned short* __restrict__ fc1w_bf, const float* __restrict__ fc1_b,
    const float* __restrict__ ln1_g, const float* __restrict__ ln1_b,
    const unsigned short* __restrict__ fc2_bf, const float* __restrict__ fc2_b,
    const float* __restrict__ ln2_g, const float* __restrict__ ln2_b,
    const unsigned short* __restrict__ fc3_bf, const float* __restrict__ fc3_b,
    unsigned short* __restrict__ fc_in)
{
  __shared__ float s_cur[4];
  __shared__ float s_cnt_clamp;
  __shared__ __align__(16) float s_nb[64][8];
  __shared__ __align__(16) float s_mask[64];
  __shared__ __align__(16) unsigned short s_act[64][SROW];
  __shared__ __align__(16) float2 s_red[4][64];
  __shared__ __align__(16) float s_part[2][128];

  const int tid  = threadIdx.x;
  const int b    = blockIdx.x;
  const int wid  = __builtin_amdgcn_readfirstlane(tid >> 6);
  const int lane = tid & 63;
  const int lr   = lane & 15, lg = lane >> 4;

  // ---- phase 0: load x row (3 + 64*5 floats), mask + count via ballot ------
  const float* xr = x_feats + (size_t)b * 323;
  if (tid < 64){
    const float* p = xr + 3 + 5*tid;
    float v0 = p[0], v1 = p[1], v2 = p[2], v3 = p[3], v4 = p[4];
    float4 q0; q0.x = v0; q0.y = v1; q0.z = v2; q0.w = v3;
    float4 q1; q1.x = v4; q1.y = 0.f; q1.z = 0.f; q1.w = 0.f;
    *(float4*)&s_nb[tid][0] = q0;
    *(float4*)&s_nb[tid][4] = q1;
    bool pr = (v0 != 0.f) || (v1 != 0.f) || (v2 != 0.f) || (v3 != 0.f) || (v4 != 0.f);
    s_mask[tid] = pr ? 1.f : 0.f;
    unsigned long long bal = __ballot(pr);
    if (tid == 0) s_cnt_clamp = fmaxf((float)__popcll(bal), 1.f);
  } else if (tid < 67){
    s_cur[tid - 64] = xr[tid - 64];
  }
  __syncthreads();

  // ---- stage 1: fc1 (K=8 pad 32), A=W1, B=x -> D rows=d ---------------------
  {
    short8 xa[4];
    #pragma unroll
    for (int nt = 0; nt < 4; nt++){
      const int row = 16*nt + lr;
      float v0=0.f,v1=0.f,v2=0.f,v3=0.f,v4=0.f,v5=0.f,v6=0.f,v7=0.f;
      if (lg == 0){
        v0 = s_cur[0]; v1 = s_cur[1]; v2 = s_cur[2];
        float4 nb = *(const float4*)&s_nb[row][0];
        v3 = nb.x; v4 = nb.y; v5 = nb.z; v6 = nb.w; v7 = s_nb[row][4];
      }
      union { short8 s8; unsigned int u[4]; } t;
      t.u[0] = cvtpk(v0, v1); t.u[1] = cvtpk(v2, v3);
      t.u[2] = cvtpk(v4, v5); t.u[3] = cvtpk(v6, v7);
      xa[nt] = t.s8;
    }
    f32x4 acc[4][4];
    const f32x4 z = {0.f,0.f,0.f,0.f};
    #pragma unroll
    for (int mt = 0; mt < 4; mt++)
      #pragma unroll
      for (int nt = 0; nt < 4; nt++) acc[mt][nt] = z;
    #pragma unroll
    for (int mt = 0; mt < 4; mt++){
      short8 bw = *(const short8*)(fc1w_bf + (size_t)(64*wid + 16*mt + lr)*32 + lg*8);
      #pragma unroll
      for (int nt = 0; nt < 4; nt++)
        acc[mt][nt] = __builtin_amdgcn_mfma_f32_16x16x32_bf16(bw, xa[nt], acc[mt][nt], 0, 0, 0);
    }
    epi_ln(acc, s_act, s_red, fc1_b, ln1_g, ln1_b, wid, lr, lg);
  }
  __syncthreads();

  // ---- stage 2: fc2 (256->256), A=W2, B=act1 -------------------------------
  {
    f32x4 acc[4][4];
    const f32x4 z = {0.f,0.f,0.f,0.f};
    #pragma unroll
    for (int mt = 0; mt < 4; mt++)
      #pragma unroll
      for (int nt = 0; nt < 4; nt++) acc[mt][nt] = z;
    #pragma unroll
    for (int kk = 0; kk < 8; kk++){
      const int k0 = kk*32 + lg*8;
      short8 xa[4];
      #pragma unroll
      for (int nt = 0; nt < 4; nt++) xa[nt] = *(const short8*)&s_act[16*nt + lr][k0];
      #pragma unroll
      for (int mt = 0; mt < 4; mt++){
        short8 bw = *(const short8*)(fc2_bf + (size_t)(64*wid + 16*mt + lr)*256 + k0);
        #pragma unroll
        for (int nt = 0; nt < 4; nt++)
          acc[mt][nt] = __builtin_amdgcn_mfma_f32_16x16x32_bf16(bw, xa[nt], acc[mt][nt], 0, 0, 0);
      }
    }
    epi_ln(acc, s_act, s_red, fc2_b, ln2_g, ln2_b, wid, lr, lg);
  }
  __syncthreads();

  // ---- stage 3: fc3 (256->128), A=act2, B=W3 -> D rows=n; transposed store -
  unsigned short (*s_embT)[TROW] = (unsigned short (*)[TROW])&s_act[0][0];
  {
    f32x4 acc3[4][2];
    const f32x4 z = {0.f,0.f,0.f,0.f};
    #pragma unroll
    for (int m = 0; m < 4; m++){ acc3[m][0] = z; acc3[m][1] = z; }
    #pragma unroll
    for (int kk = 0; kk < 8; kk++){
      const int k0 = kk*32 + lg*8;
      short8 a[4];
      #pragma unroll
      for (int m = 0; m < 4; m++) a[m] = *(const short8*)&s_act[16*m + lr][k0];
      #pragma unroll
      for (int t4 = 0; t4 < 2; t4++){
        short8 bw = *(const short8*)(fc3_bf + (size_t)(32*wid + 16*t4 + lr)*256 + k0);
        #pragma unroll
        for (int m = 0; m < 4; m++)
          acc3[m][t4] = __builtin_amdgcn_mfma_f32_16x16x32_bf16(a[m], bw, acc3[m][t4], 0, 0, 0);
      }
    }
    __syncthreads();   // all waves done reading act2 -> safe to alias s_embT
    #pragma unroll
    for (int t4 = 0; t4 < 2; t4++){
      const int col = 32*wid + 16*t4 + lr;
      const float bias = fc3_b[col];
      #pragma unroll
      for (int m = 0; m < 4; m++){
        u32x2 o;
        o[0] = cvtpk(acc3[m][t4][0] + bias, acc3[m][t4][1] + bias);
        o[1] = cvtpk(acc3[m][t4][2] + bias, acc3[m][t4][3] + bias);
        *(u32x2*)&s_embT[col][16*m + 4*lg] = o;
      }
    }
  }
  __syncthreads();

  // ---- phase 4: masked mean-pool + gather -> fc_in[b][288] -----------------
  {
    const int aidx = actions[b];
    unsigned short* fo = fc_in + (size_t)b * 288;
    {
      const int d = tid & 127, h = tid >> 7;
      const unsigned short* er = s_embT[d] + 32*h;
      float ax = 0.f, ay = 0.f;
      #pragma unroll
      for (int u = 0; u < 8; u++){
        u32x2 w2 = *(const u32x2*)(er + 4*u);
        float2 m0 = *(const float2*)&s_mask[32*h + 4*u];
        float2 m1 = *(const float2*)&s_mask[32*h + 4*u + 2];
        unsigned int a0 = w2[0], a1 = w2[1];
        float x0 = __uint_as_float(a0 << 16), x1 = __uint_as_float(a0 & 0xffff0000u);
        float x2 = __uint_as_float(a1 << 16), x3 = __uint_as_float(a1 & 0xffff0000u);
        ax = fmaf(x0, m0.x, ax); ay = fmaf(x1, m0.y, ay);
        ax = fmaf(x2, m1.x, ax); ay = fmaf(x3, m1.y, ay);
      }
      s_part[h][d] = ax + ay;
    }
    __syncthreads();
    if (tid < 128){
      float tot = s_part[0][tid] + s_part[1][tid];
      fo[131 + tid] = f2bf(tot / s_cnt_clamp);  // pooled
      fo[3 + tid]   = s_embT[tid][aidx];        // chosen embed
    } else if (tid < 160){
      const int t = tid - 128;
      if (t < 3)       fo[t] = f2bf(s_cur[t]);
      else if (t < 8)  fo[259 + (t-3)] = f2bf(s_nb[aidx][t-3]);
      else             fo[264 + (t-8)] = 0;   // zero pad K->288
    }
  }
}

// ---------------- head: fc_in[B][288] -> f1 -> LN -> lrelu -> f2 -> out[B] --
__global__ __launch_bounds__(256, 2) void qnet_head(
    const unsigned short* __restrict__ fc_in,   // [B][288] bf16
    const unsigned short* __restrict__ f1_bf,   // [512][288] bf16
    const float* __restrict__ f1_b,
    const float* __restrict__ lnf_g, const float* __restrict__ lnf_b,
    const float* __restrict__ f2_w, const float* __restrict__ f2_b,
    float* __restrict__ out)
{
  __shared__ __align__(16) unsigned short s_fin[16][296];
  __shared__ __align__(16) float s_pre[16][520];
  const int tid = threadIdx.x;
  const int r0  = blockIdx.x * 16;
  const int wid = tid >> 6, lane = tid & 63;
  const int lr  = lane & 15, lg = lane >> 4;

  for (int i = tid; i < 16*36; i += 256){
    int r = i / 36, cc = (i % 36) * 8;
    *(short8*)&s_fin[r][cc] = *(const short8*)(fc_in + (size_t)(r0 + r) * 288 + cc);
  }
  __syncthreads();

  {
    f32x4 acc[8];
    const f32x4 z = {0.f, 0.f, 0.f, 0.f};
    #pragma unroll
    for (int t = 0; t < 8; t++) acc[t] = z;
    #pragma unroll
    for (int kk = 0; kk < 9; kk++){
      const int k0 = kk*32 + lg*8;
      short8 a = *(const short8*)&s_fin[lr][k0];
      #pragma unroll
      for (int t = 0; t < 8; t++){
        short8 bw = *(const short8*)(f1_bf + (size_t)(128*wid + 16*t + lr) * 288 + k0);
        acc[t] = __builtin_amdgcn_mfma_f32_16x16x32_bf16(a, bw, acc[t], 0, 0, 0);
      }
    }
    #pragma unroll
    for (int t = 0; t < 8; t++){
      const int col = 128*wid + 16*t + lr;
      const float bias = f1_b[col];
      #pragma unroll
      for (int j = 0; j < 4; j++){
        const int row = 4*lg + j;
        s_pre[row][col] = acc[t][j] + bias;
      }
    }
  }
  __syncthreads();

  {
    const int c0 = lane * 8;
    float g8[8], b8[8], w8[8];
    #pragma unroll
    for (int j = 0; j < 8; j++){ g8[j] = lnf_g[c0+j]; b8[j] = lnf_b[c0+j]; w8[j] = f2_w[c0+j]; }
    for (int r = wid*4; r < wid*4 + 4; r++){
      float x[8];
      #pragma unroll
      for (int j = 0; j < 8; j++) x[j] = s_pre[r][c0+j];
      float s = 0.f, s2 = 0.f;
      #pragma unroll
      for (int j = 0; j < 8; j++){ s += x[j]; s2 += x[j]*x[j]; }
      #pragma unroll
      for (int m = 1; m < 64; m <<= 1){ s += __shfl_xor(s, m, 64); s2 += __shfl_xor(s2, m, 64); }
      float mean = s * (1.f/512.f);
      float var  = s2 * (1.f/512.f) - mean*mean;
      float rstd = rsqrtf(var + LN_EPS);
      float dot = 0.f;
      #pragma unroll
      for (int j = 0; j < 8; j++){
        float y = (x[j]-mean)*rstd*g8[j] + b8[j];
        y = fmaxf(y, NSLOPE*y);
        dot += y * w8[j];
      }
      #pragma unroll
      for (int m = 1; m < 64; m <<= 1) dot += __shfl_xor(dot, m, 64);
      if (lane == 0) out[r0 + r] = dot + f2_b[0];
    }
  }
}

extern "C" void kernel_launch(void* const* d_in, const int* in_sizes, int n_in,
                              void* d_out, int out_size, void* d_ws, size_t ws_size,
                              hipStream_t stream)
{
  const float* x_feats = (const float*)d_in[0];
  const int*   actions = (const int*)d_in[1];
  const float* fc1_w = (const float*)d_in[2];  const float* fc1_b = (const float*)d_in[3];
  const float* ln1_g = (const float*)d_in[4];  const float* ln1_b = (const float*)d_in[5];
  const float* fc2_w = (const float*)d_in[6];  const float* fc2_b = (const float*)d_in[7];
  const float* ln2_g = (const float*)d_in[8];  const float* ln2_b = (const float*)d_in[9];
  const float* fc3_w = (const float*)d_in[10]; const float* fc3_b = (const float*)d_in[11];
  const float* f1_w  = (const float*)d_in[12]; const float* f1_b  = (const float*)d_in[13];
  const float* lnf_g = (const float*)d_in[14]; const float* lnf_b = (const float*)d_in[15];
  const float* f2_w  = (const float*)d_in[16]; const float* f2_b  = (const float*)d_in[17];

  const int B = in_sizes[1];  // 4096

  unsigned short* fc2_bf  = (unsigned short*)d_ws;
  unsigned short* fc3_bf  = fc2_bf + 256*256;
  unsigned short* f1_bf   = fc3_bf + 128*256;
  unsigned short* fc1w_bf = f1_bf  + 512*288;
  unsigned short* fc_in   = fc1w_bf + 256*32;

  qnet_prep<<<dim3(992), dim3(256), 0, stream>>>(fc1_w, fc2_w, fc3_w, f1_w,
      fc1w_bf, fc2_bf, fc3_bf, f1_bf);
  qnet_main<<<dim3(B), dim3(256), 0, stream>>>(x_feats, actions,
      fc1w_bf, fc1_b, ln1_g, ln1_b, fc2_bf, fc2_b, ln2_g, ln2_b, fc3_bf, fc3_b, fc_in);
  qnet_head<<<dim3(B/16), dim3(256), 0, stream>>>(fc_in, f1_bf, f1_b, lnf_g, lnf_b, f2_w, f2_b,
      (float*)d_out);
}